// Round 18
// baseline (322.317 us; speedup 1.0000x reference)
//
#include <hip/hip_runtime.h>
#include <hip/hip_bf16.h>

#define LOG2E 1.4426950408889634f

typedef __attribute__((ext_vector_type(8))) __bf16 bf16x8;
typedef __attribute__((ext_vector_type(2))) __bf16 bf16x2;
typedef __attribute__((ext_vector_type(4))) float f32x4;
typedef __attribute__((ext_vector_type(16))) float f32x16;

#define MFMA16(a,b,c) __builtin_amdgcn_mfma_f32_16x16x32_bf16((a),(b),(c),0,0,0)
#define MFMA32(a,b,c) __builtin_amdgcn_mfma_f32_32x32x16_bf16((a),(b),(c),0,0,0)

#define GLL16(g, l) __builtin_amdgcn_global_load_lds( \
    (const __attribute__((address_space(1))) void*)(g), \
    (__attribute__((address_space(3))) void*)(l), 16, 0, 0)

__device__ __forceinline__ unsigned short bfu(float f) {
    __bf16 h = (__bf16)f; unsigned short u; __builtin_memcpy(&u, &h, 2); return u;
}
__device__ __forceinline__ unsigned cvtpk(float lo, float hi) {
    bf16x2 t; t.x = (__bf16)lo; t.y = (__bf16)hi;
    unsigned r; __builtin_memcpy(&r, &t, 4); return r;
}
__device__ __forceinline__ bf16x8 pack4(unsigned a, unsigned b, unsigned c, unsigned d) {
    union { unsigned u[4]; bf16x8 v; } t; t.u[0]=a; t.u[1]=b; t.u[2]=c; t.u[3]=d; return t.v;
}
__device__ __forceinline__ bf16x8 cvt8(float4 a, float4 b, float s) {
    bf16x8 o;
    o[0]=(__bf16)(a.x*s); o[1]=(__bf16)(a.y*s); o[2]=(__bf16)(a.z*s); o[3]=(__bf16)(a.w*s);
    o[4]=(__bf16)(b.x*s); o[5]=(__bf16)(b.y*s); o[6]=(__bf16)(b.z*s); o[7]=(__bf16)(b.w*s);
    return o;
}

// Fragment-order layouts for attention operands (one 1KB coalesced load per
// 64-lane group; also the exact HW pattern of global_load_lds -> linear LDS):
//  Kg: [bh][kt][f=half*4+dc][lane=hi*32+l31][e] = K[kt*64+half*32+l31][dc*16+hi*8+e]
//  Vg: [bh][kt][g=kc*2+v1][lane=hi*32+l31][e]  = V[kt*64+kc*16+4*hi+8*(e>>2)+(e&3)][v1*32+l31]
__device__ __forceinline__ size_t kidx(int bh, int s, int d) {
    int kt = s>>6, half=(s>>5)&1, l31k=s&31;
    int dc=d>>4, hik=(d>>3)&1, e=d&7;
    return (((size_t)bh*32+kt)*8 + half*4+dc)*512 + (hik*32+l31k)*8 + e;
}
__device__ __forceinline__ size_t vidx(int bh, int s, int d) {
    int kt=s>>6, kvin=s&63, kc=kvin>>4, rem=kvin&15;
    int hiv=(rem>>2)&1, e=(rem&3)+4*(rem>>3);
    int v1=d>>5, l31v=d&31;
    return (((size_t)bh*32+kt)*8 + kc*2+v1)*512 + (hiv*32+l31v)*8 + e;
}

// ---------------------------------------------------------------------------
// Conversion: q,k,v [4096x1024] and Wq,Wk,Wv,Wo [1024x1024] fp32 -> bf16.
// Wq pre-scaled by 0.125*log2e (folds attention scale + exp2 domain).
// ---------------------------------------------------------------------------
__global__ __launch_bounds__(256)
void conv_kernel(const float* __restrict__ q, const float* __restrict__ k,
                 const float* __restrict__ v, const float* __restrict__ Wq,
                 const float* __restrict__ Wk, const float* __restrict__ Wv,
                 const float* __restrict__ Wo, unsigned short* __restrict__ Xb,
                 unsigned short* __restrict__ Wb)
{
    const int y = blockIdx.y;
    if (y < 3) {
        const float* s = (y==0)?q:(y==1)?k:v;
        size_t i = ((size_t)blockIdx.x*256 + threadIdx.x)*8;
        float4 a = *(const float4*)(s+i), b = *(const float4*)(s+i+4);
        *(bf16x8*)(Xb + (size_t)y*4194304 + i) = cvt8(a, b, 1.0f);
    } else {
        const int w = blockIdx.x >> 9;
        const float* s = (w==0)?Wq:(w==1)?Wk:(w==2)?Wv:Wo;
        const float sc = (w==0) ? 0.125f*LOG2E : 1.0f;
        size_t i = ((size_t)(blockIdx.x & 511)*256 + threadIdx.x)*8;
        float4 a = *(const float4*)(s+i), b = *(const float4*)(s+i+4);
        *(bf16x8*)(Wb + (size_t)w*1048576 + i) = cvt8(a, b, sc);
    }
}

// ---------------------------------------------------------------------------
// Fused QKV projection: out_z = X_z @ W_z^T. Tile 128x128, 4 waves, BK=32,
// 3 LDS buffers, stage-1-ahead, counted vmcnt(4), single barrier per K-step.
// global_load_lds w=16, XOR-swizzled. grid (32,8,3).
// ---------------------------------------------------------------------------
__global__ __launch_bounds__(256)
void qkv_kernel(const unsigned short* __restrict__ Xb,
                const unsigned short* __restrict__ Wb,
                unsigned short* __restrict__ Qh, unsigned short* __restrict__ Kg,
                unsigned short* __restrict__ Vg)
{
    __shared__ unsigned short As[3][4096];
    __shared__ unsigned short Bs[3][4096];
    const int z = blockIdx.z;
    const unsigned short* X = Xb + (size_t)z*4194304;
    const unsigned short* W = Wb + (size_t)z*1048576;
    const int t = threadIdx.x, wid = t>>6, lane = t&63;
    const int m0 = blockIdx.x*128, n0 = blockIdx.y*128;
    const int wr = (wid>>1)*64, wc = (wid&1)*64;
    const int lr = lane&15, lk = lane>>4;

    f32x4 acc[4][4] = {};

#define STAGEQ(ktile, buf) do { \
    const int K0_ = (ktile)*32; \
    _Pragma("unroll") \
    for (int i_=0;i_<2;++i_){ \
        int flat_ = i_*4096 + wid*1024 + lane*16; \
        int row_ = flat_>>6, cb_ = (flat_&63) ^ ((row_&3)<<4); \
        GLL16(X + (size_t)(m0+row_)*1024 + K0_ + (cb_>>1), (char*)&As[buf][0] + i_*4096 + wid*1024); \
        GLL16(W + (size_t)(n0+row_)*1024 + K0_ + (cb_>>1), (char*)&Bs[buf][0] + i_*4096 + wid*1024); \
    } } while (0)

    STAGEQ(0, 0);

    for (int kt=0; kt<32; ++kt){
        const int cur = kt % 3;
        if (kt < 31) {
            STAGEQ(kt+1, (kt+1)%3);
            asm volatile("s_waitcnt vmcnt(4)" ::: "memory");
        } else {
            asm volatile("s_waitcnt vmcnt(0)" ::: "memory");
        }
        __builtin_amdgcn_s_barrier();
        asm volatile("" ::: "memory");

        bf16x8 a[4], b[4];
#pragma unroll
        for (int i=0;i<4;++i){
            int row = wr+i*16+lr;
            a[i] = *(const bf16x8*)((const char*)&As[cur][0] + row*64 + ((lk*16)^((row&3)<<4)));
        }
#pragma unroll
        for (int j=0;j<4;++j){
            int row = wc+j*16+lr;
            b[j] = *(const bf16x8*)((const char*)&Bs[cur][0] + row*64 + ((lk*16)^((row&3)<<4)));
        }
#pragma unroll
        for (int i=0;i<4;++i)
#pragma unroll
            for (int j=0;j<4;++j)
                acc[i][j] = MFMA16(a[i], b[j], acc[i][j]);
    }
#undef STAGEQ

#pragma unroll
    for (int i=0;i<4;++i)
#pragma unroll
      for (int j=0;j<4;++j)
#pragma unroll
        for (int r=0;r<4;++r){
            int m = m0 + wr + i*16 + lk*4 + r;
            int n = n0 + wc + j*16 + lr;
            int b_ = m>>11, s = m&2047;
            int h = n>>6, d = n&63;
            int bh = b_*16 + h;
            unsigned short val = bfu(acc[i][j][r]);
            if (z==0)      Qh[((size_t)bh*2048 + s)*64 + d] = val;
            else if (z==1) Kg[kidx(bh, s, d)] = val;
            else           Vg[vidx(bh, s, d)] = val;
        }
}

// ---------------------------------------------------------------------------
// Output projection: out = Oh(gathered) @ Wo^T, fp32. Tile 128x64, BK=64,
// all-bf16 global_load_lds staging. grid (32,16).
// ---------------------------------------------------------------------------
__global__ __launch_bounds__(256)
void oproj_kernel(const unsigned short* __restrict__ Oh,
                  const unsigned short* __restrict__ Wo,
                  float* __restrict__ out)
{
    __shared__ unsigned short As[2][8192];
    __shared__ unsigned short Bs2[2][4096];
    const int t = threadIdx.x, wid = t>>6, lane = t&63;
    const int m0 = blockIdx.x*128, n0 = blockIdx.y*64;
    const int wr = (wid>>1)*64, wc = (wid&1)*32;
    const int lr = lane&15, lk = lane>>4;
    const int fbase = wid*1024 + lane*16;

    f32x4 acc[4][2] = {};

#pragma unroll
    for (int i=0;i<4;++i){
        int flat = i*4096 + fbase, row = flat>>7;
        int cb = (flat&127) ^ ((row&7)<<4);
        int m = m0+row, b_ = m>>11, s = m&2047;
        GLL16(Oh + ((size_t)(b_*16+0)*2048 + s)*64 + (cb>>1), (char*)&As[0][0] + i*4096 + wid*1024);
    }
#pragma unroll
    for (int i=0;i<2;++i){
        int flat = i*4096 + fbase, row = flat>>7;
        int cb = (flat&127) ^ ((row&7)<<4);
        GLL16(Wo + (size_t)(n0+row)*1024 + (cb>>1), (char*)&Bs2[0][0] + i*4096 + wid*1024);
    }

    for (int kt=0; kt<16; ++kt){
        const int cur = kt&1;
        if (kt<15){
            const int nb = cur^1, K0 = (kt+1)*64, h = K0>>6;
#pragma unroll
            for (int i=0;i<4;++i){
                int flat = i*4096 + fbase, row = flat>>7;
                int cb = (flat&127) ^ ((row&7)<<4);
                int m = m0+row, b_ = m>>11, s = m&2047;
                GLL16(Oh + ((size_t)(b_*16+h)*2048 + s)*64 + (cb>>1),
                      (char*)&As[nb][0] + i*4096 + wid*1024);
            }
#pragma unroll
            for (int i=0;i<2;++i){
                int flat = i*4096 + fbase, row = flat>>7;
                int cb = (flat&127) ^ ((row&7)<<4);
                GLL16(Wo + (size_t)(n0+row)*1024 + K0 + (cb>>1),
                      (char*)&Bs2[nb][0] + i*4096 + wid*1024);
            }
            asm volatile("s_waitcnt vmcnt(6)" ::: "memory");
        } else {
            asm volatile("s_waitcnt vmcnt(0)" ::: "memory");
        }
        __builtin_amdgcn_s_barrier();
        asm volatile("" ::: "memory");

        bf16x8 a[4][2], b[2][2];
#pragma unroll
        for (int i=0;i<4;++i){
            int row = wr+i*16+lr, sw = (row&7)<<4;
            const char* rp = (const char*)&As[cur][0] + row*128;
#pragma unroll
            for (int ks=0;ks<2;++ks)
                a[i][ks] = *(const bf16x8*)(rp + ((ks*64 + lk*16)^sw));
        }
#pragma unroll
        for (int j=0;j<2;++j){
            int row = wc+j*16+lr, sw = (row&7)<<4;
            const char* rp = (const char*)&Bs2[cur][0] + row*128;
#pragma unroll
            for (int ks=0;ks<2;++ks)
                b[j][ks] = *(const bf16x8*)(rp + ((ks*64 + lk*16)^sw));
        }
#pragma unroll
        for (int i=0;i<4;++i)
#pragma unroll
          for (int j=0;j<2;++j)
#pragma unroll
            for (int ks=0;ks<2;++ks)
                acc[i][j] = MFMA16(a[i][ks], b[j][ks], acc[i][j]);
        asm volatile("" ::: "memory");
        __builtin_amdgcn_s_barrier();
    }

#pragma unroll
    for (int i=0;i<4;++i)
#pragma unroll
      for (int j=0;j<2;++j)
#pragma unroll
        for (int r=0;r<4;++r){
            int m = m0 + wr + i*16 + lk*4 + r;
            int n = n0 + wc + j*16 + lr;
            out[(size_t)m*1024 + n] = acc[i][j][r];
        }
}

// ---------------------------------------------------------------------------
// Flash attention, SPLIT-KV: 8-wave blocks (512 thr); waves 0-3 process
// kv-tiles 0-15, waves 4-7 tiles 16-31 for the SAME 128 q-rows. Fixed-shift
// softmax makes partials combine by pure addition (exact): O=O0+O1, l=l0+l1.
// 4096 waves total = 4 waves/SIMD (vs 2) -- the TLP the 32q layout couldn't
// reach. Per-half body = r16's proven form: K fragment-order LDS (4 buffers/
// half), stage-2-ahead, single barrier/iter, manual vmcnt(2); V direct from
// L2. End merge via (dead) Ks as conflict-free f32 columns. grid 512.
// ---------------------------------------------------------------------------
__global__ __launch_bounds__(512, 4)
void attn_kernel(const unsigned short* __restrict__ Qh,
                 const unsigned short* __restrict__ Kg,
                 const unsigned short* __restrict__ Vg,
                 const int* __restrict__ mask,
                 unsigned short* __restrict__ Oh)
{
    __shared__ unsigned short Ks[8][4096];   // [half*4 + buf]; merge scratch after loop

    const int t = threadIdx.x, wid = t >> 6, lane = t & 63;
    const int qwid = wid & 3, half = wid >> 2;
    const int l31 = lane & 31, hi = lane >> 5;
    const int linb = blockIdx.x + 16*blockIdx.y;   // 512 works
    const int work = (linb & 7)*64 + (linb >> 3);  // 64-work chunk per XCD
    const int bh = work >> 4;
    const int q0 = (work & 15) * 128;
    const int b_ = bh >> 4;
    const int qw = q0 + qwid*32 + l31;

    unsigned flagbits;
    {
        const int4* mp = (const int4*)(mask + b_*2048 + (lane&31)*64);
        int bad = 0;
#pragma unroll
        for (int i=0;i<16;++i){ int4 m4 = mp[i];
            bad |= (m4.x==0)|(m4.y==0)|(m4.z==0)|(m4.w==0); }
        unsigned long long bm = __ballot(bad);
        flagbits = (unsigned)bm;
    }

    bf16x8 qf[4];
    const unsigned short* Qp = Qh + ((size_t)bh*2048 + qw)*64 + hi*8;
#pragma unroll
    for (int dc = 0; dc < 4; ++dc) qf[dc] = *(const bf16x8*)(Qp + dc*16);

    // this half's 16 tiles
    const unsigned short* Kbase = Kg + (size_t)bh*131072 + (size_t)half*65536;
    const unsigned short* Vb2   = Vg + (size_t)bh*131072 + (size_t)half*65536 + lane*8;

    // wave stages K groups qwid*2, qwid*2+1 into its half's buffer set
#define STAGE(j) do { if ((j) < 16) { \
    const unsigned short* Kt_ = Kbase + (size_t)(j)*4096; \
    _Pragma("unroll") \
    for (int i_ = 0; i_ < 2; ++i_) { \
        int g_ = qwid*2 + i_; \
        GLL16(Kt_ + g_*512 + lane*8, &Ks[half*4 + ((j)&3)][g_*512]); \
    } } } while (0)

    STAGE(0);
    STAGE(1);

    f32x16 o0a = {}, o0b = {}, o1a = {}, o1b = {};
    float l_run = 0.0f;
    f32x16 minit;
#pragma unroll
    for (int r = 0; r < 16; ++r) minit[r] = -12.0f;

    for (int i = 0; i < 16; ++i) {
        const int kt = half*16 + i;
        if (i < 15) asm volatile("s_waitcnt vmcnt(2)" ::: "memory");
        else        asm volatile("s_waitcnt vmcnt(0)" ::: "memory");
        __builtin_amdgcn_s_barrier();   // single barrier per iteration
        asm volatile("" ::: "memory");

        // K fragments from LDS (conflict-free)
        bf16x8 kb[8];
#pragma unroll
        for (int f = 0; f < 8; ++f)
            kb[f] = *(const bf16x8*)&Ks[half*4 + (i&3)][f*512 + lane*8];

        // V fragments direct from L2 (coalesced 1KB loads)
        bf16x8 vf[8];
        {
            const unsigned short* vp = Vb2 + (size_t)i*4096;
#pragma unroll
            for (int g = 0; g < 8; ++g) vf[g] = *(const bf16x8*)(vp + g*512);
        }
        asm volatile("" ::: "memory");   // pin V loads before STAGE

        // S^T - 12 = K Q^T + (-12), two interleaved 4-deep chains
        f32x16 s0, s1;
#pragma unroll
        for (int dc = 0; dc < 4; ++dc) {
            if (dc == 0) { s0 = MFMA32(kb[0], qf[0], minit); s1 = MFMA32(kb[4], qf[0], minit); }
            else         { s0 = MFMA32(kb[dc], qf[dc], s0);  s1 = MFMA32(kb[4+dc], qf[dc], s1); }
        }

        STAGE(i + 2);
        asm volatile("" ::: "memory");

        if (flagbits & (1u << kt)) {
            const int* mrow = mask + b_*2048 + kt*64;
#pragma unroll
            for (int r = 0; r < 16; ++r) {
                int kv = (r&3) + 8*(r>>2) + 4*hi;
                if (mrow[kv] == 0)      s0[r] = -1e9f;
                if (mrow[32 + kv] == 0) s1[r] = -1e9f;
            }
        }

        // p = exp2(s - 12), fixed shift
#pragma unroll
        for (int r = 0; r < 16; ++r) {
            s0[r] = __builtin_amdgcn_exp2f(s0[r]);
            s1[r] = __builtin_amdgcn_exp2f(s1[r]);
        }

        // l row-sum for q=l31 (halves merged once after the loop)
        {
            float rs = 0.0f;
#pragma unroll
            for (int r = 0; r < 16; ++r) rs += s0[r] + s1[r];
            l_run += rs;
        }

        // pi-permuted A-fragments: registers in natural order, no exchange
        bf16x8 pa[4];
        pa[0] = pack4(cvtpk(s0[0],s0[1]),  cvtpk(s0[2],s0[3]),
                      cvtpk(s0[4],s0[5]),  cvtpk(s0[6],s0[7]));
        pa[1] = pack4(cvtpk(s0[8],s0[9]),  cvtpk(s0[10],s0[11]),
                      cvtpk(s0[12],s0[13]),cvtpk(s0[14],s0[15]));
        pa[2] = pack4(cvtpk(s1[0],s1[1]),  cvtpk(s1[2],s1[3]),
                      cvtpk(s1[4],s1[5]),  cvtpk(s1[6],s1[7]));
        pa[3] = pack4(cvtpk(s1[8],s1[9]),  cvtpk(s1[10],s1[11]),
                      cvtpk(s1[12],s1[13]),cvtpk(s1[14],s1[15]));

        // O += P' V'  with split accumulators (2-deep chains)
        o0a = MFMA32(pa[0], vf[0], o0a);
        o1a = MFMA32(pa[0], vf[1], o1a);
        o0b = MFMA32(pa[1], vf[2], o0b);
        o1b = MFMA32(pa[1], vf[3], o1b);
        o0a = MFMA32(pa[2], vf[4], o0a);
        o1a = MFMA32(pa[2], vf[5], o1a);
        o0b = MFMA32(pa[3], vf[6], o0b);
        o1b = MFMA32(pa[3], vf[7], o1b);
    }
#undef STAGE

    // merge split accumulators and hi/lo l halves (within this kv-half)
    f32x16 o0, o1;
#pragma unroll
    for (int r = 0; r < 16; ++r) { o0[r] = o0a[r] + o0b[r]; o1[r] = o1a[r] + o1b[r]; }
    float l_tot = l_run + __shfl_xor(l_run, 32);

    // ---- cross-half merge via (now dead) Ks: pure addition, exact ----
    __syncthreads();
    float* Mf = (float*)&Ks[0][0];
    if (half == 1) {
        float* M = Mf + qwid*2112;     // 33*64 floats per qwid
#pragma unroll
        for (int r = 0; r < 16; ++r) {
            M[r*64 + lane]      = o0[r];
            M[(16+r)*64 + lane] = o1[r];
        }
        M[2048 + lane] = l_tot;
    }
    __syncthreads();
    if (half == 0) {
        const float* M = Mf + qwid*2112;
#pragma unroll
        for (int r = 0; r < 16; ++r) {
            o0[r] += M[r*64 + lane];
            o1[r] += M[(16+r)*64 + lane];
        }
        l_tot += M[2048 + lane];

        // wave-local LDS transpose: l[l31] -> crow-indexed cc[16]
        float cc[16];
        {
            float* Lb = Mf + 8448 + qwid*64;
            Lb[l31] = l_tot;
            asm volatile("s_waitcnt lgkmcnt(0)" ::: "memory");
#pragma unroll
            for (int g = 0; g < 4; ++g) {
                float4 v = *(const float4*)&Lb[g*8 + hi*4];
                cc[4*g]=v.x; cc[4*g+1]=v.y; cc[4*g+2]=v.z; cc[4*g+3]=v.w;
            }
        }

        unsigned short* Ob = Oh + ((size_t)bh*2048 + q0 + qwid*32)*64;
#pragma unroll
        for (int r = 0; r < 16; ++r) {
            int qr = (r&3) + 8*(r>>2) + 4*hi;
            float inv = 1.0f / cc[r];
            Ob[(size_t)qr*64 + l31]      = bfu(o0[r] * inv);
            Ob[(size_t)qr*64 + 32 + l31] = bfu(o1[r] * inv);
        }
    }
}

// ---------------------------------------------------------------------------
extern "C" void kernel_launch(void* const* d_in, const int* in_sizes, int n_in,
                              void* d_out, int out_size, void* d_ws, size_t ws_size,
                              hipStream_t stream)
{
    const float* q  = (const float*)d_in[0];
    const float* k  = (const float*)d_in[1];
    const float* v  = (const float*)d_in[2];
    const int* mask = (const int*)d_in[3];
    const float* Wq = (const float*)d_in[4];
    const float* Wk = (const float*)d_in[5];
    const float* Wv = (const float*)d_in[6];
    const float* Wo = (const float*)d_in[7];
    float* out = (float*)d_out;

    // ws (ushort elems): Xb 12M | Wb 4M | Qh 4M | Kg 4M | Vg 4M  = 56MB.
    // Oh aliases Xb (Xb is dead after qkv_kernel).
    unsigned short* Xb = (unsigned short*)d_ws;
    unsigned short* Wb = Xb + (size_t)12582912;
    unsigned short* Qh = Wb + (size_t)4194304;
    unsigned short* Kg = Qh + (size_t)4194304;
    unsigned short* Vg = Kg + (size_t)4194304;
    unsigned short* Oh = Xb;

    conv_kernel<<<dim3(2048,4), 256, 0, stream>>>(q, k, v, Wq, Wk, Wv, Wo, Xb, Wb);
    qkv_kernel<<<dim3(32,8,3), 256, 0, stream>>>(Xb, Wb, Qh, Kg, Vg);
    attn_kernel<<<dim3(16,32), 512, 0, stream>>>(Qh, Kg, Vg, mask, Oh);
    oproj_kernel<<<dim3(32,16), 256, 0, stream>>>(Oh, Wb + (size_t)3145728, out);
}

// Round 19
// 127.552 us; speedup vs baseline: 2.5269x; 2.5269x over previous
//
#include <hip/hip_runtime.h>
#include <hip/hip_bf16.h>

#define LOG2E 1.4426950408889634f

typedef __attribute__((ext_vector_type(8))) __bf16 bf16x8;
typedef __attribute__((ext_vector_type(2))) __bf16 bf16x2;
typedef __attribute__((ext_vector_type(4))) float f32x4;
typedef __attribute__((ext_vector_type(16))) float f32x16;

#define MFMA16(a,b,c) __builtin_amdgcn_mfma_f32_16x16x32_bf16((a),(b),(c),0,0,0)
#define MFMA32(a,b,c) __builtin_amdgcn_mfma_f32_32x32x16_bf16((a),(b),(c),0,0,0)

#define GLL16(g, l) __builtin_amdgcn_global_load_lds( \
    (const __attribute__((address_space(1))) void*)(g), \
    (__attribute__((address_space(3))) void*)(l), 16, 0, 0)

__device__ __forceinline__ unsigned short bfu(float f) {
    __bf16 h = (__bf16)f; unsigned short u; __builtin_memcpy(&u, &h, 2); return u;
}
__device__ __forceinline__ unsigned cvtpk(float lo, float hi) {
    bf16x2 t; t.x = (__bf16)lo; t.y = (__bf16)hi;
    unsigned r; __builtin_memcpy(&r, &t, 4); return r;
}
__device__ __forceinline__ bf16x8 pack4(unsigned a, unsigned b, unsigned c, unsigned d) {
    union { unsigned u[4]; bf16x8 v; } t; t.u[0]=a; t.u[1]=b; t.u[2]=c; t.u[3]=d; return t.v;
}
__device__ __forceinline__ bf16x8 cvt8(float4 a, float4 b, float s) {
    bf16x8 o;
    o[0]=(__bf16)(a.x*s); o[1]=(__bf16)(a.y*s); o[2]=(__bf16)(a.z*s); o[3]=(__bf16)(a.w*s);
    o[4]=(__bf16)(b.x*s); o[5]=(__bf16)(b.y*s); o[6]=(__bf16)(b.z*s); o[7]=(__bf16)(b.w*s);
    return o;
}

// Fragment-order layouts for attention operands (one 1KB coalesced load per
// 64-lane group; also the exact HW pattern of global_load_lds -> linear LDS):
//  Kg: [bh][kt][f=half*4+dc][lane=hi*32+l31][e] = K[kt*64+half*32+l31][dc*16+hi*8+e]
//  Vg: [bh][kt][g=kc*2+v1][lane=hi*32+l31][e]  = V[kt*64+kc*16+4*hi+8*(e>>2)+(e&3)][v1*32+l31]
__device__ __forceinline__ size_t kidx(int bh, int s, int d) {
    int kt = s>>6, half=(s>>5)&1, l31k=s&31;
    int dc=d>>4, hik=(d>>3)&1, e=d&7;
    return (((size_t)bh*32+kt)*8 + half*4+dc)*512 + (hik*32+l31k)*8 + e;
}
__device__ __forceinline__ size_t vidx(int bh, int s, int d) {
    int kt=s>>6, kvin=s&63, kc=kvin>>4, rem=kvin&15;
    int hiv=(rem>>2)&1, e=(rem&3)+4*(rem>>3);
    int v1=d>>5, l31v=d&31;
    return (((size_t)bh*32+kt)*8 + kc*2+v1)*512 + (hiv*32+l31v)*8 + e;
}

// ---------------------------------------------------------------------------
// Conversion: q,k,v [4096x1024] and Wq,Wk,Wv,Wo [1024x1024] fp32 -> bf16.
// Wq pre-scaled by 0.125*log2e (folds attention scale + exp2 domain).
// ---------------------------------------------------------------------------
__global__ __launch_bounds__(256)
void conv_kernel(const float* __restrict__ q, const float* __restrict__ k,
                 const float* __restrict__ v, const float* __restrict__ Wq,
                 const float* __restrict__ Wk, const float* __restrict__ Wv,
                 const float* __restrict__ Wo, unsigned short* __restrict__ Xb,
                 unsigned short* __restrict__ Wb)
{
    const int y = blockIdx.y;
    if (y < 3) {
        const float* s = (y==0)?q:(y==1)?k:v;
        size_t i = ((size_t)blockIdx.x*256 + threadIdx.x)*8;
        float4 a = *(const float4*)(s+i), b = *(const float4*)(s+i+4);
        *(bf16x8*)(Xb + (size_t)y*4194304 + i) = cvt8(a, b, 1.0f);
    } else {
        const int w = blockIdx.x >> 9;
        const float* s = (w==0)?Wq:(w==1)?Wk:(w==2)?Wv:Wo;
        const float sc = (w==0) ? 0.125f*LOG2E : 1.0f;
        size_t i = ((size_t)(blockIdx.x & 511)*256 + threadIdx.x)*8;
        float4 a = *(const float4*)(s+i), b = *(const float4*)(s+i+4);
        *(bf16x8*)(Wb + (size_t)w*1048576 + i) = cvt8(a, b, sc);
    }
}

// ---------------------------------------------------------------------------
// Fused QKV projection: out_z = X_z @ W_z^T. Tile 128x128, 4 waves, BK=32,
// 3 LDS buffers, stage-1-ahead, counted vmcnt(4), single barrier per K-step.
// global_load_lds w=16, XOR-swizzled. grid (32,8,3).
// ---------------------------------------------------------------------------
__global__ __launch_bounds__(256)
void qkv_kernel(const unsigned short* __restrict__ Xb,
                const unsigned short* __restrict__ Wb,
                unsigned short* __restrict__ Qh, unsigned short* __restrict__ Kg,
                unsigned short* __restrict__ Vg)
{
    __shared__ unsigned short As[3][4096];
    __shared__ unsigned short Bs[3][4096];
    const int z = blockIdx.z;
    const unsigned short* X = Xb + (size_t)z*4194304;
    const unsigned short* W = Wb + (size_t)z*1048576;
    const int t = threadIdx.x, wid = t>>6, lane = t&63;
    const int m0 = blockIdx.x*128, n0 = blockIdx.y*128;
    const int wr = (wid>>1)*64, wc = (wid&1)*64;
    const int lr = lane&15, lk = lane>>4;

    f32x4 acc[4][4] = {};

#define STAGEQ(ktile, buf) do { \
    const int K0_ = (ktile)*32; \
    _Pragma("unroll") \
    for (int i_=0;i_<2;++i_){ \
        int flat_ = i_*4096 + wid*1024 + lane*16; \
        int row_ = flat_>>6, cb_ = (flat_&63) ^ ((row_&3)<<4); \
        GLL16(X + (size_t)(m0+row_)*1024 + K0_ + (cb_>>1), (char*)&As[buf][0] + i_*4096 + wid*1024); \
        GLL16(W + (size_t)(n0+row_)*1024 + K0_ + (cb_>>1), (char*)&Bs[buf][0] + i_*4096 + wid*1024); \
    } } while (0)

    STAGEQ(0, 0);

    for (int kt=0; kt<32; ++kt){
        const int cur = kt % 3;
        if (kt < 31) {
            STAGEQ(kt+1, (kt+1)%3);
            asm volatile("s_waitcnt vmcnt(4)" ::: "memory");
        } else {
            asm volatile("s_waitcnt vmcnt(0)" ::: "memory");
        }
        __builtin_amdgcn_s_barrier();
        asm volatile("" ::: "memory");

        bf16x8 a[4], b[4];
#pragma unroll
        for (int i=0;i<4;++i){
            int row = wr+i*16+lr;
            a[i] = *(const bf16x8*)((const char*)&As[cur][0] + row*64 + ((lk*16)^((row&3)<<4)));
        }
#pragma unroll
        for (int j=0;j<4;++j){
            int row = wc+j*16+lr;
            b[j] = *(const bf16x8*)((const char*)&Bs[cur][0] + row*64 + ((lk*16)^((row&3)<<4)));
        }
#pragma unroll
        for (int i=0;i<4;++i)
#pragma unroll
            for (int j=0;j<4;++j)
                acc[i][j] = MFMA16(a[i], b[j], acc[i][j]);
    }
#undef STAGEQ

#pragma unroll
    for (int i=0;i<4;++i)
#pragma unroll
      for (int j=0;j<4;++j)
#pragma unroll
        for (int r=0;r<4;++r){
            int m = m0 + wr + i*16 + lk*4 + r;
            int n = n0 + wc + j*16 + lr;
            int b_ = m>>11, s = m&2047;
            int h = n>>6, d = n&63;
            int bh = b_*16 + h;
            unsigned short val = bfu(acc[i][j][r]);
            if (z==0)      Qh[((size_t)bh*2048 + s)*64 + d] = val;
            else if (z==1) Kg[kidx(bh, s, d)] = val;
            else           Vg[vidx(bh, s, d)] = val;
        }
}

// ---------------------------------------------------------------------------
// Output projection: out = Oh(gathered) @ Wo^T, fp32. Tile 128x64, BK=64,
// all-bf16 global_load_lds staging. grid (32,16).
// ---------------------------------------------------------------------------
__global__ __launch_bounds__(256)
void oproj_kernel(const unsigned short* __restrict__ Oh,
                  const unsigned short* __restrict__ Wo,
                  float* __restrict__ out)
{
    __shared__ unsigned short As[2][8192];
    __shared__ unsigned short Bs2[2][4096];
    const int t = threadIdx.x, wid = t>>6, lane = t&63;
    const int m0 = blockIdx.x*128, n0 = blockIdx.y*64;
    const int wr = (wid>>1)*64, wc = (wid&1)*32;
    const int lr = lane&15, lk = lane>>4;
    const int fbase = wid*1024 + lane*16;

    f32x4 acc[4][2] = {};

#pragma unroll
    for (int i=0;i<4;++i){
        int flat = i*4096 + fbase, row = flat>>7;
        int cb = (flat&127) ^ ((row&7)<<4);
        int m = m0+row, b_ = m>>11, s = m&2047;
        GLL16(Oh + ((size_t)(b_*16+0)*2048 + s)*64 + (cb>>1), (char*)&As[0][0] + i*4096 + wid*1024);
    }
#pragma unroll
    for (int i=0;i<2;++i){
        int flat = i*4096 + fbase, row = flat>>7;
        int cb = (flat&127) ^ ((row&7)<<4);
        GLL16(Wo + (size_t)(n0+row)*1024 + (cb>>1), (char*)&Bs2[0][0] + i*4096 + wid*1024);
    }

    for (int kt=0; kt<16; ++kt){
        const int cur = kt&1;
        if (kt<15){
            const int nb = cur^1, K0 = (kt+1)*64, h = K0>>6;
#pragma unroll
            for (int i=0;i<4;++i){
                int flat = i*4096 + fbase, row = flat>>7;
                int cb = (flat&127) ^ ((row&7)<<4);
                int m = m0+row, b_ = m>>11, s = m&2047;
                GLL16(Oh + ((size_t)(b_*16+h)*2048 + s)*64 + (cb>>1),
                      (char*)&As[nb][0] + i*4096 + wid*1024);
            }
#pragma unroll
            for (int i=0;i<2;++i){
                int flat = i*4096 + fbase, row = flat>>7;
                int cb = (flat&127) ^ ((row&7)<<4);
                GLL16(Wo + (size_t)(n0+row)*1024 + K0 + (cb>>1),
                      (char*)&Bs2[nb][0] + i*4096 + wid*1024);
            }
            asm volatile("s_waitcnt vmcnt(6)" ::: "memory");
        } else {
            asm volatile("s_waitcnt vmcnt(0)" ::: "memory");
        }
        __builtin_amdgcn_s_barrier();
        asm volatile("" ::: "memory");

        bf16x8 a[4][2], b[2][2];
#pragma unroll
        for (int i=0;i<4;++i){
            int row = wr+i*16+lr, sw = (row&7)<<4;
            const char* rp = (const char*)&As[cur][0] + row*128;
#pragma unroll
            for (int ks=0;ks<2;++ks)
                a[i][ks] = *(const bf16x8*)(rp + ((ks*64 + lk*16)^sw));
        }
#pragma unroll
        for (int j=0;j<2;++j){
            int row = wc+j*16+lr, sw = (row&7)<<4;
            const char* rp = (const char*)&Bs2[cur][0] + row*128;
#pragma unroll
            for (int ks=0;ks<2;++ks)
                b[j][ks] = *(const bf16x8*)(rp + ((ks*64 + lk*16)^sw));
        }
#pragma unroll
        for (int i=0;i<4;++i)
#pragma unroll
          for (int j=0;j<2;++j)
#pragma unroll
            for (int ks=0;ks<2;++ks)
                acc[i][j] = MFMA16(a[i][ks], b[j][ks], acc[i][j]);
        asm volatile("" ::: "memory");
        __builtin_amdgcn_s_barrier();
    }

#pragma unroll
    for (int i=0;i<4;++i)
#pragma unroll
      for (int j=0;j<2;++j)
#pragma unroll
        for (int r=0;r<4;++r){
            int m = m0 + wr + i*16 + lk*4 + r;
            int n = n0 + wc + j*16 + lr;
            out[(size_t)m*1024 + n] = acc[i][j][r];
        }
}

// ---------------------------------------------------------------------------
// Flash attention, SPLIT-KV: 8-wave blocks (512 thr); waves 0-3 process
// kv-tiles 0-15, waves 4-7 tiles 16-31 for the SAME 128 q-rows. Fixed-shift
// softmax makes partials combine by pure addition (exact): O=O0+O1, l=l0+l1.
// 4096 waves total = 4 waves/SIMD. launch_bounds(512, 2): 2 blocks/CU =
// 16 waves/CU = 4 waves/SIMD -> 128 VGPR budget (r18's (512,4) forced 64
// VGPR -> total spill; that bug, not the structure, caused the 252us).
// Per-half body = r16's proven form. Merge via dead Ks. grid 512.
// ---------------------------------------------------------------------------
__global__ __launch_bounds__(512, 2)
void attn_kernel(const unsigned short* __restrict__ Qh,
                 const unsigned short* __restrict__ Kg,
                 const unsigned short* __restrict__ Vg,
                 const int* __restrict__ mask,
                 unsigned short* __restrict__ Oh)
{
    __shared__ unsigned short Ks[8][4096];   // [half*4 + buf]; merge scratch after loop

    const int t = threadIdx.x, wid = t >> 6, lane = t & 63;
    const int qwid = wid & 3, half = wid >> 2;
    const int l31 = lane & 31, hi = lane >> 5;
    const int linb = blockIdx.x + 16*blockIdx.y;   // 512 works
    const int work = (linb & 7)*64 + (linb >> 3);  // 64-work chunk per XCD
    const int bh = work >> 4;
    const int q0 = (work & 15) * 128;
    const int b_ = bh >> 4;
    const int qw = q0 + qwid*32 + l31;

    unsigned flagbits;
    {
        const int4* mp = (const int4*)(mask + b_*2048 + (lane&31)*64);
        int bad = 0;
#pragma unroll
        for (int i=0;i<16;++i){ int4 m4 = mp[i];
            bad |= (m4.x==0)|(m4.y==0)|(m4.z==0)|(m4.w==0); }
        unsigned long long bm = __ballot(bad);
        flagbits = (unsigned)bm;
    }

    bf16x8 qf[4];
    const unsigned short* Qp = Qh + ((size_t)bh*2048 + qw)*64 + hi*8;
#pragma unroll
    for (int dc = 0; dc < 4; ++dc) qf[dc] = *(const bf16x8*)(Qp + dc*16);

    // this half's 16 tiles
    const unsigned short* Kbase = Kg + (size_t)bh*131072 + (size_t)half*65536;
    const unsigned short* Vb2   = Vg + (size_t)bh*131072 + (size_t)half*65536 + lane*8;

    // wave stages K groups qwid*2, qwid*2+1 into its half's buffer set
#define STAGE(j) do { if ((j) < 16) { \
    const unsigned short* Kt_ = Kbase + (size_t)(j)*4096; \
    _Pragma("unroll") \
    for (int i_ = 0; i_ < 2; ++i_) { \
        int g_ = qwid*2 + i_; \
        GLL16(Kt_ + g_*512 + lane*8, &Ks[half*4 + ((j)&3)][g_*512]); \
    } } } while (0)

    STAGE(0);
    STAGE(1);

    f32x16 o0a = {}, o0b = {}, o1a = {}, o1b = {};
    float l_run = 0.0f;
    f32x16 minit;
#pragma unroll
    for (int r = 0; r < 16; ++r) minit[r] = -12.0f;

    for (int i = 0; i < 16; ++i) {
        const int kt = half*16 + i;
        if (i < 15) asm volatile("s_waitcnt vmcnt(2)" ::: "memory");
        else        asm volatile("s_waitcnt vmcnt(0)" ::: "memory");
        __builtin_amdgcn_s_barrier();   // single barrier per iteration
        asm volatile("" ::: "memory");

        // K fragments from LDS (conflict-free)
        bf16x8 kb[8];
#pragma unroll
        for (int f = 0; f < 8; ++f)
            kb[f] = *(const bf16x8*)&Ks[half*4 + (i&3)][f*512 + lane*8];

        // V fragments direct from L2 (coalesced 1KB loads)
        bf16x8 vf[8];
        {
            const unsigned short* vp = Vb2 + (size_t)i*4096;
#pragma unroll
            for (int g = 0; g < 8; ++g) vf[g] = *(const bf16x8*)(vp + g*512);
        }
        asm volatile("" ::: "memory");   // pin V loads before STAGE

        // S^T - 12 = K Q^T + (-12), two interleaved 4-deep chains
        f32x16 s0, s1;
#pragma unroll
        for (int dc = 0; dc < 4; ++dc) {
            if (dc == 0) { s0 = MFMA32(kb[0], qf[0], minit); s1 = MFMA32(kb[4], qf[0], minit); }
            else         { s0 = MFMA32(kb[dc], qf[dc], s0);  s1 = MFMA32(kb[4+dc], qf[dc], s1); }
        }

        STAGE(i + 2);
        asm volatile("" ::: "memory");

        if (flagbits & (1u << kt)) {
            const int* mrow = mask + b_*2048 + kt*64;
#pragma unroll
            for (int r = 0; r < 16; ++r) {
                int kv = (r&3) + 8*(r>>2) + 4*hi;
                if (mrow[kv] == 0)      s0[r] = -1e9f;
                if (mrow[32 + kv] == 0) s1[r] = -1e9f;
            }
        }

        // p = exp2(s - 12), fixed shift
#pragma unroll
        for (int r = 0; r < 16; ++r) {
            s0[r] = __builtin_amdgcn_exp2f(s0[r]);
            s1[r] = __builtin_amdgcn_exp2f(s1[r]);
        }

        // l row-sum for q=l31 (halves merged once after the loop)
        {
            float rs = 0.0f;
#pragma unroll
            for (int r = 0; r < 16; ++r) rs += s0[r] + s1[r];
            l_run += rs;
        }

        // pi-permuted A-fragments: registers in natural order, no exchange
        bf16x8 pa[4];
        pa[0] = pack4(cvtpk(s0[0],s0[1]),  cvtpk(s0[2],s0[3]),
                      cvtpk(s0[4],s0[5]),  cvtpk(s0[6],s0[7]));
        pa[1] = pack4(cvtpk(s0[8],s0[9]),  cvtpk(s0[10],s0[11]),
                      cvtpk(s0[12],s0[13]),cvtpk(s0[14],s0[15]));
        pa[2] = pack4(cvtpk(s1[0],s1[1]),  cvtpk(s1[2],s1[3]),
                      cvtpk(s1[4],s1[5]),  cvtpk(s1[6],s1[7]));
        pa[3] = pack4(cvtpk(s1[8],s1[9]),  cvtpk(s1[10],s1[11]),
                      cvtpk(s1[12],s1[13]),cvtpk(s1[14],s1[15]));

        // O += P' V'  with split accumulators (2-deep chains)
        o0a = MFMA32(pa[0], vf[0], o0a);
        o1a = MFMA32(pa[0], vf[1], o1a);
        o0b = MFMA32(pa[1], vf[2], o0b);
        o1b = MFMA32(pa[1], vf[3], o1b);
        o0a = MFMA32(pa[2], vf[4], o0a);
        o1a = MFMA32(pa[2], vf[5], o1a);
        o0b = MFMA32(pa[3], vf[6], o0b);
        o1b = MFMA32(pa[3], vf[7], o1b);
    }
#undef STAGE

    // merge split accumulators and hi/lo l halves (within this kv-half)
    f32x16 o0, o1;
#pragma unroll
    for (int r = 0; r < 16; ++r) { o0[r] = o0a[r] + o0b[r]; o1[r] = o1a[r] + o1b[r]; }
    float l_tot = l_run + __shfl_xor(l_run, 32);

    // ---- cross-half merge via (now dead) Ks: pure addition, exact ----
    __syncthreads();
    float* Mf = (float*)&Ks[0][0];
    if (half == 1) {
        float* M = Mf + qwid*2112;     // 33*64 floats per qwid
#pragma unroll
        for (int r = 0; r < 16; ++r) {
            M[r*64 + lane]      = o0[r];
            M[(16+r)*64 + lane] = o1[r];
        }
        M[2048 + lane] = l_tot;
    }
    __syncthreads();
    if (half == 0) {
        const float* M = Mf + qwid*2112;
#pragma unroll
        for (int r = 0; r < 16; ++r) {
            o0[r] += M[r*64 + lane];
            o1[r] += M[(16+r)*64 + lane];
        }
        l_tot += M[2048 + lane];

        // wave-local LDS transpose: l[l31] -> crow-indexed cc[16]
        float cc[16];
        {
            float* Lb = Mf + 8448 + qwid*64;
            Lb[l31] = l_tot;
            asm volatile("s_waitcnt lgkmcnt(0)" ::: "memory");
#pragma unroll
            for (int g = 0; g < 4; ++g) {
                float4 v = *(const float4*)&Lb[g*8 + hi*4];
                cc[4*g]=v.x; cc[4*g+1]=v.y; cc[4*g+2]=v.z; cc[4*g+3]=v.w;
            }
        }

        unsigned short* Ob = Oh + ((size_t)bh*2048 + q0 + qwid*32)*64;
#pragma unroll
        for (int r = 0; r < 16; ++r) {
            int qr = (r&3) + 8*(r>>2) + 4*hi;
            float inv = 1.0f / cc[r];
            Ob[(size_t)qr*64 + l31]      = bfu(o0[r] * inv);
            Ob[(size_t)qr*64 + 32 + l31] = bfu(o1[r] * inv);
        }
    }
}

// ---------------------------------------------------------------------------
extern "C" void kernel_launch(void* const* d_in, const int* in_sizes, int n_in,
                              void* d_out, int out_size, void* d_ws, size_t ws_size,
                              hipStream_t stream)
{
    const float* q  = (const float*)d_in[0];
    const float* k  = (const float*)d_in[1];
    const float* v  = (const float*)d_in[2];
    const int* mask = (const int*)d_in[3];
    const float* Wq = (const float*)d_in[4];
    const float* Wk = (const float*)d_in[5];
    const float* Wv = (const float*)d_in[6];
    const float* Wo = (const float*)d_in[7];
    float* out = (float*)d_out;

    // ws (ushort elems): Xb 12M | Wb 4M | Qh 4M | Kg 4M | Vg 4M  = 56MB.
    // Oh aliases Xb (Xb is dead after qkv_kernel).
    unsigned short* Xb = (unsigned short*)d_ws;
    unsigned short* Wb = Xb + (size_t)12582912;
    unsigned short* Qh = Wb + (size_t)4194304;
    unsigned short* Kg = Qh + (size_t)4194304;
    unsigned short* Vg = Kg + (size_t)4194304;
    unsigned short* Oh = Xb;

    conv_kernel<<<dim3(2048,4), 256, 0, stream>>>(q, k, v, Wq, Wk, Wv, Wo, Xb, Wb);
    qkv_kernel<<<dim3(32,8,3), 256, 0, stream>>>(Xb, Wb, Qh, Kg, Vg);
    attn_kernel<<<dim3(16,32), 512, 0, stream>>>(Qh, Kg, Vg, mask, Oh);
    oproj_kernel<<<dim3(32,16), 256, 0, stream>>>(Oh, Wb + (size_t)3145728, out);
}

// Round 20
// 117.740 us; speedup vs baseline: 2.7375x; 1.0833x over previous
//
#include <hip/hip_runtime.h>
#include <hip/hip_bf16.h>

#define LOG2E 1.4426950408889634f

typedef __attribute__((ext_vector_type(8))) __bf16 bf16x8;
typedef __attribute__((ext_vector_type(2))) __bf16 bf16x2;
typedef __attribute__((ext_vector_type(4))) float f32x4;
typedef __attribute__((ext_vector_type(16))) float f32x16;

#define MFMA16(a,b,c) __builtin_amdgcn_mfma_f32_16x16x32_bf16((a),(b),(c),0,0,0)
#define MFMA32(a,b,c) __builtin_amdgcn_mfma_f32_32x32x16_bf16((a),(b),(c),0,0,0)

#define GLL16(g, l) __builtin_amdgcn_global_load_lds( \
    (const __attribute__((address_space(1))) void*)(g), \
    (__attribute__((address_space(3))) void*)(l), 16, 0, 0)

__device__ __forceinline__ unsigned short bfu(float f) {
    __bf16 h = (__bf16)f; unsigned short u; __builtin_memcpy(&u, &h, 2); return u;
}
__device__ __forceinline__ unsigned cvtpk(float lo, float hi) {
    bf16x2 t; t.x = (__bf16)lo; t.y = (__bf16)hi;
    unsigned r; __builtin_memcpy(&r, &t, 4); return r;
}
__device__ __forceinline__ bf16x8 pack4(unsigned a, unsigned b, unsigned c, unsigned d) {
    union { unsigned u[4]; bf16x8 v; } t; t.u[0]=a; t.u[1]=b; t.u[2]=c; t.u[3]=d; return t.v;
}
__device__ __forceinline__ bf16x8 cvt8(float4 a, float4 b, float s) {
    bf16x8 o;
    o[0]=(__bf16)(a.x*s); o[1]=(__bf16)(a.y*s); o[2]=(__bf16)(a.z*s); o[3]=(__bf16)(a.w*s);
    o[4]=(__bf16)(b.x*s); o[5]=(__bf16)(b.y*s); o[6]=(__bf16)(b.z*s); o[7]=(__bf16)(b.w*s);
    return o;
}

// Fragment-order layouts for attention operands (one 1KB coalesced load per
// 64-lane group; also the exact HW pattern of global_load_lds -> linear LDS):
//  Kg: [bh][kt][f=half*4+dc][lane=hi*32+l31][e] = K[kt*64+half*32+l31][dc*16+hi*8+e]
//  Vg: [bh][kt][g=kc*2+v1][lane=hi*32+l31][e]  = V[kt*64+kc*16+4*hi+8*(e>>2)+(e&3)][v1*32+l31]
__device__ __forceinline__ size_t kidx(int bh, int s, int d) {
    int kt = s>>6, half=(s>>5)&1, l31k=s&31;
    int dc=d>>4, hik=(d>>3)&1, e=d&7;
    return (((size_t)bh*32+kt)*8 + half*4+dc)*512 + (hik*32+l31k)*8 + e;
}
__device__ __forceinline__ size_t vidx(int bh, int s, int d) {
    int kt=s>>6, kvin=s&63, kc=kvin>>4, rem=kvin&15;
    int hiv=(rem>>2)&1, e=(rem&3)+4*(rem>>3);
    int v1=d>>5, l31v=d&31;
    return (((size_t)bh*32+kt)*8 + kc*2+v1)*512 + (hiv*32+l31v)*8 + e;
}

// ---------------------------------------------------------------------------
// Conversion: q,k,v [4096x1024] and Wq,Wk,Wv,Wo [1024x1024] fp32 -> bf16.
// Wq pre-scaled by 0.125*log2e (folds attention scale + exp2 domain).
// ---------------------------------------------------------------------------
__global__ __launch_bounds__(256)
void conv_kernel(const float* __restrict__ q, const float* __restrict__ k,
                 const float* __restrict__ v, const float* __restrict__ Wq,
                 const float* __restrict__ Wk, const float* __restrict__ Wv,
                 const float* __restrict__ Wo, unsigned short* __restrict__ Xb,
                 unsigned short* __restrict__ Wb)
{
    const int y = blockIdx.y;
    if (y < 3) {
        const float* s = (y==0)?q:(y==1)?k:v;
        size_t i = ((size_t)blockIdx.x*256 + threadIdx.x)*8;
        float4 a = *(const float4*)(s+i), b = *(const float4*)(s+i+4);
        *(bf16x8*)(Xb + (size_t)y*4194304 + i) = cvt8(a, b, 1.0f);
    } else {
        const int w = blockIdx.x >> 9;
        const float* s = (w==0)?Wq:(w==1)?Wk:(w==2)?Wv:Wo;
        const float sc = (w==0) ? 0.125f*LOG2E : 1.0f;
        size_t i = ((size_t)(blockIdx.x & 511)*256 + threadIdx.x)*8;
        float4 a = *(const float4*)(s+i), b = *(const float4*)(s+i+4);
        *(bf16x8*)(Wb + (size_t)w*1048576 + i) = cvt8(a, b, sc);
    }
}

// ---------------------------------------------------------------------------
// Fused QKV projection: out_z = X_z @ W_z^T. Tile 128x128, 4 waves, BK=32,
// 3 LDS buffers, stage-1-ahead, counted vmcnt(4), single barrier per K-step.
// global_load_lds w=16, XOR-swizzled. grid (32,8,3).
// ---------------------------------------------------------------------------
__global__ __launch_bounds__(256)
void qkv_kernel(const unsigned short* __restrict__ Xb,
                const unsigned short* __restrict__ Wb,
                unsigned short* __restrict__ Qh, unsigned short* __restrict__ Kg,
                unsigned short* __restrict__ Vg)
{
    __shared__ unsigned short As[3][4096];
    __shared__ unsigned short Bs[3][4096];
    const int z = blockIdx.z;
    const unsigned short* X = Xb + (size_t)z*4194304;
    const unsigned short* W = Wb + (size_t)z*1048576;
    const int t = threadIdx.x, wid = t>>6, lane = t&63;
    const int m0 = blockIdx.x*128, n0 = blockIdx.y*128;
    const int wr = (wid>>1)*64, wc = (wid&1)*64;
    const int lr = lane&15, lk = lane>>4;

    f32x4 acc[4][4] = {};

#define STAGEQ(ktile, buf) do { \
    const int K0_ = (ktile)*32; \
    _Pragma("unroll") \
    for (int i_=0;i_<2;++i_){ \
        int flat_ = i_*4096 + wid*1024 + lane*16; \
        int row_ = flat_>>6, cb_ = (flat_&63) ^ ((row_&3)<<4); \
        GLL16(X + (size_t)(m0+row_)*1024 + K0_ + (cb_>>1), (char*)&As[buf][0] + i_*4096 + wid*1024); \
        GLL16(W + (size_t)(n0+row_)*1024 + K0_ + (cb_>>1), (char*)&Bs[buf][0] + i_*4096 + wid*1024); \
    } } while (0)

    STAGEQ(0, 0);

    for (int kt=0; kt<32; ++kt){
        const int cur = kt % 3;
        if (kt < 31) {
            STAGEQ(kt+1, (kt+1)%3);
            asm volatile("s_waitcnt vmcnt(4)" ::: "memory");
        } else {
            asm volatile("s_waitcnt vmcnt(0)" ::: "memory");
        }
        __builtin_amdgcn_s_barrier();
        asm volatile("" ::: "memory");

        bf16x8 a[4], b[4];
#pragma unroll
        for (int i=0;i<4;++i){
            int row = wr+i*16+lr;
            a[i] = *(const bf16x8*)((const char*)&As[cur][0] + row*64 + ((lk*16)^((row&3)<<4)));
        }
#pragma unroll
        for (int j=0;j<4;++j){
            int row = wc+j*16+lr;
            b[j] = *(const bf16x8*)((const char*)&Bs[cur][0] + row*64 + ((lk*16)^((row&3)<<4)));
        }
#pragma unroll
        for (int i=0;i<4;++i)
#pragma unroll
            for (int j=0;j<4;++j)
                acc[i][j] = MFMA16(a[i], b[j], acc[i][j]);
    }
#undef STAGEQ

#pragma unroll
    for (int i=0;i<4;++i)
#pragma unroll
      for (int j=0;j<4;++j)
#pragma unroll
        for (int r=0;r<4;++r){
            int m = m0 + wr + i*16 + lk*4 + r;
            int n = n0 + wc + j*16 + lr;
            int b_ = m>>11, s = m&2047;
            int h = n>>6, d = n&63;
            int bh = b_*16 + h;
            unsigned short val = bfu(acc[i][j][r]);
            if (z==0)      Qh[((size_t)bh*2048 + s)*64 + d] = val;
            else if (z==1) Kg[kidx(bh, s, d)] = val;
            else           Vg[vidx(bh, s, d)] = val;
        }
}

// ---------------------------------------------------------------------------
// Output projection: out = Oh(gathered) @ Wo^T, fp32. Tile 128x64, BK=64,
// 3 LDS buffers (72KB; grid 512 = 2 blocks/CU regardless), stage-1-ahead,
// counted vmcnt(6), SINGLE barrier per K-step (qkv's proven pattern).
// ---------------------------------------------------------------------------
__global__ __launch_bounds__(256)
void oproj_kernel(const unsigned short* __restrict__ Oh,
                  const unsigned short* __restrict__ Wo,
                  float* __restrict__ out)
{
    __shared__ unsigned short As[3][8192];
    __shared__ unsigned short Bs2[3][4096];
    const int t = threadIdx.x, wid = t>>6, lane = t&63;
    const int m0 = blockIdx.x*128, n0 = blockIdx.y*64;
    const int wr = (wid>>1)*64, wc = (wid&1)*32;
    const int lr = lane&15, lk = lane>>4;
    const int fbase = wid*1024 + lane*16;

    f32x4 acc[4][2] = {};

#define STAGEO(ktile, buf) do { \
    const int K0_ = (ktile)*64, h_ = K0_>>6; \
    _Pragma("unroll") \
    for (int i_=0;i_<4;++i_){ \
        int flat_ = i_*4096 + fbase, row_ = flat_>>7; \
        int cb_ = (flat_&127) ^ ((row_&7)<<4); \
        int m_ = m0+row_, bb_ = m_>>11, s_ = m_&2047; \
        GLL16(Oh + ((size_t)(bb_*16+h_)*2048 + s_)*64 + (cb_>>1), \
              (char*)&As[buf][0] + i_*4096 + wid*1024); \
    } \
    _Pragma("unroll") \
    for (int i_=0;i_<2;++i_){ \
        int flat_ = i_*4096 + fbase, row_ = flat_>>7; \
        int cb_ = (flat_&127) ^ ((row_&7)<<4); \
        GLL16(Wo + (size_t)(n0+row_)*1024 + K0_ + (cb_>>1), \
              (char*)&Bs2[buf][0] + i_*4096 + wid*1024); \
    } } while (0)

    STAGEO(0, 0);

    for (int kt=0; kt<16; ++kt){
        const int cur = kt % 3;
        if (kt < 15) {
            STAGEO(kt+1, (kt+1)%3);
            asm volatile("s_waitcnt vmcnt(6)" ::: "memory");
        } else {
            asm volatile("s_waitcnt vmcnt(0)" ::: "memory");
        }
        __builtin_amdgcn_s_barrier();
        asm volatile("" ::: "memory");

        bf16x8 a[4][2], b[2][2];
#pragma unroll
        for (int i=0;i<4;++i){
            int row = wr+i*16+lr, sw = (row&7)<<4;
            const char* rp = (const char*)&As[cur][0] + row*128;
#pragma unroll
            for (int ks=0;ks<2;++ks)
                a[i][ks] = *(const bf16x8*)(rp + ((ks*64 + lk*16)^sw));
        }
#pragma unroll
        for (int j=0;j<2;++j){
            int row = wc+j*16+lr, sw = (row&7)<<4;
            const char* rp = (const char*)&Bs2[cur][0] + row*128;
#pragma unroll
            for (int ks=0;ks<2;++ks)
                b[j][ks] = *(const bf16x8*)(rp + ((ks*64 + lk*16)^sw));
        }
#pragma unroll
        for (int i=0;i<4;++i)
#pragma unroll
          for (int j=0;j<2;++j)
#pragma unroll
            for (int ks=0;ks<2;++ks)
                acc[i][j] = MFMA16(a[i][ks], b[j][ks], acc[i][j]);
    }
#undef STAGEO

#pragma unroll
    for (int i=0;i<4;++i)
#pragma unroll
      for (int j=0;j<2;++j)
#pragma unroll
        for (int r=0;r<4;++r){
            int m = m0 + wr + i*16 + lk*4 + r;
            int n = n0 + wc + j*16 + lr;
            out[(size_t)m*1024 + n] = acc[i][j][r];
        }
}

// ---------------------------------------------------------------------------
// Flash attention (r16, proven 46.2us): K via fragment-order LDS staging
// (4 buffers, 32KB, stage-2-ahead, single barrier/tile, manual vmcnt(2));
// V read DIRECTLY from L2 in fragment order (8 coalesced 1KB loads/wave/
// tile). 4-wave blocks (q=128), grid 512, 32q/wave (2 waves/SIMD).
// Fixed-shift softmax (m=12 in C-in); pi-permuted PV; split PV accumulators;
// l via in-lane row-sum + shfl + LDS transpose. XCD swizzle.
// ---------------------------------------------------------------------------
__global__ __launch_bounds__(256, 2)
void attn_kernel(const unsigned short* __restrict__ Qh,
                 const unsigned short* __restrict__ Kg,
                 const unsigned short* __restrict__ Vg,
                 const int* __restrict__ mask,
                 unsigned short* __restrict__ Oh)
{
    __shared__ unsigned short Ks[4][4096];   // K only: 8 groups x 512 per buf

    const int t = threadIdx.x, wid = t >> 6, lane = t & 63;
    const int l31 = lane & 31, hi = lane >> 5;
    const int linb = blockIdx.x + 16*blockIdx.y;   // 512 works
    const int work = (linb & 7)*64 + (linb >> 3);  // 64-work chunk per XCD
    const int bh = work >> 4;
    const int q0 = (work & 15) * 128;
    const int b_ = bh >> 4;
    const int qw = q0 + wid*32 + l31;

    unsigned flagbits;
    {
        const int4* mp = (const int4*)(mask + b_*2048 + (lane&31)*64);
        int bad = 0;
#pragma unroll
        for (int i=0;i<16;++i){ int4 m4 = mp[i];
            bad |= (m4.x==0)|(m4.y==0)|(m4.z==0)|(m4.w==0); }
        unsigned long long bm = __ballot(bad);
        flagbits = (unsigned)bm;
    }

    bf16x8 qf[4];
    const unsigned short* Qp = Qh + ((size_t)bh*2048 + qw)*64 + hi*8;
#pragma unroll
    for (int dc = 0; dc < 4; ++dc) qf[dc] = *(const bf16x8*)(Qp + dc*16);

    const unsigned short* Kbase = Kg + (size_t)bh*131072;
    const unsigned short* Vb2   = Vg + (size_t)bh*131072 + lane*8;

    // wave stages K groups wid*2, wid*2+1 (2 GLL16/wave/tile)
#define STAGE(ktile, buf) do { \
    const unsigned short* Kt_ = Kbase + (size_t)(ktile)*4096; \
    _Pragma("unroll") \
    for (int i_ = 0; i_ < 2; ++i_) { \
        int g_ = wid*2 + i_; \
        GLL16(Kt_ + g_*512 + lane*8, &Ks[buf][g_*512]); \
    } } while (0)

    STAGE(0, 0);
    STAGE(1, 1);

    f32x16 o0a = {}, o0b = {}, o1a = {}, o1b = {};
    float l_run = 0.0f;
    f32x16 minit;
#pragma unroll
    for (int r = 0; r < 16; ++r) minit[r] = -12.0f;

    for (int kt = 0; kt < 32; ++kt) {
        const int cur = kt & 3;
        // tile kt's K (staged 2 iters ago) is older than the 2 loads of
        // STAGE(kt+1) still in flight -> vmcnt(2) proves it landed.
        if (kt < 31) asm volatile("s_waitcnt vmcnt(2)" ::: "memory");
        else         asm volatile("s_waitcnt vmcnt(0)" ::: "memory");
        __builtin_amdgcn_s_barrier();
        asm volatile("" ::: "memory");

        // K fragments from LDS (conflict-free: 64 consecutive lanes/group)
        bf16x8 kb[8];
#pragma unroll
        for (int f = 0; f < 8; ++f) kb[f] = *(const bf16x8*)&Ks[cur][f*512 + lane*8];

        // V fragments DIRECT from L2 (coalesced 1KB loads). Issued before
        // STAGE(kt+2): compiler's wait for vf at PV = vmcnt(2).
        bf16x8 vf[8];
        {
            const unsigned short* vp = Vb2 + (size_t)kt*4096;
#pragma unroll
            for (int g = 0; g < 8; ++g) vf[g] = *(const bf16x8*)(vp + g*512);
        }
        asm volatile("" ::: "memory");   // pin V loads before STAGE

        // S^T - 12 = K Q^T + (-12), two interleaved 4-deep chains
        f32x16 s0, s1;
#pragma unroll
        for (int dc = 0; dc < 4; ++dc) {
            if (dc == 0) { s0 = MFMA32(kb[0], qf[0], minit); s1 = MFMA32(kb[4], qf[0], minit); }
            else         { s0 = MFMA32(kb[dc], qf[dc], s0);  s1 = MFMA32(kb[4+dc], qf[dc], s1); }
        }

        if (kt + 2 < 32) STAGE(kt + 2, (kt + 2) & 3);
        asm volatile("" ::: "memory");

        if (flagbits & (1u << kt)) {
            const int* mrow = mask + b_*2048 + kt*64;
#pragma unroll
            for (int r = 0; r < 16; ++r) {
                int kv = (r&3) + 8*(r>>2) + 4*hi;
                if (mrow[kv] == 0)      s0[r] = -1e9f;
                if (mrow[32 + kv] == 0) s1[r] = -1e9f;
            }
        }

        // p = exp2(s - 12), fixed shift
#pragma unroll
        for (int r = 0; r < 16; ++r) {
            s0[r] = __builtin_amdgcn_exp2f(s0[r]);
            s1[r] = __builtin_amdgcn_exp2f(s1[r]);
        }

        // l row-sum for q=l31 (halves merged once after the loop)
        {
            float rs = 0.0f;
#pragma unroll
            for (int r = 0; r < 16; ++r) rs += s0[r] + s1[r];
            l_run += rs;
        }

        // pi-permuted A-fragments: registers in natural order, no exchange
        bf16x8 pa[4];
        pa[0] = pack4(cvtpk(s0[0],s0[1]),  cvtpk(s0[2],s0[3]),
                      cvtpk(s0[4],s0[5]),  cvtpk(s0[6],s0[7]));
        pa[1] = pack4(cvtpk(s0[8],s0[9]),  cvtpk(s0[10],s0[11]),
                      cvtpk(s0[12],s0[13]),cvtpk(s0[14],s0[15]));
        pa[2] = pack4(cvtpk(s1[0],s1[1]),  cvtpk(s1[2],s1[3]),
                      cvtpk(s1[4],s1[5]),  cvtpk(s1[6],s1[7]));
        pa[3] = pack4(cvtpk(s1[8],s1[9]),  cvtpk(s1[10],s1[11]),
                      cvtpk(s1[12],s1[13]),cvtpk(s1[14],s1[15]));

        // O += P' V'  with split accumulators (2-deep chains)
        o0a = MFMA32(pa[0], vf[0], o0a);
        o1a = MFMA32(pa[0], vf[1], o1a);
        o0b = MFMA32(pa[1], vf[2], o0b);
        o1b = MFMA32(pa[1], vf[3], o1b);
        o0a = MFMA32(pa[2], vf[4], o0a);
        o1a = MFMA32(pa[2], vf[5], o1a);
        o0b = MFMA32(pa[3], vf[6], o0b);
        o1b = MFMA32(pa[3], vf[7], o1b);
    }
#undef STAGE

    // merge split accumulators and hi/lo l halves
    f32x16 o0, o1;
#pragma unroll
    for (int r = 0; r < 16; ++r) { o0[r] = o0a[r] + o0b[r]; o1[r] = o1a[r] + o1b[r]; }
    float l_tot = l_run + __shfl_xor(l_run, 32);

    // wave-local LDS transpose: l[l31] -> crow-indexed cc[16]
    float cc[16];
    {
        float* Lb = (float*)((char*)&Ks[0][0] + wid*256);
        Lb[l31] = l_tot;
        asm volatile("s_waitcnt lgkmcnt(0)" ::: "memory");
#pragma unroll
        for (int g = 0; g < 4; ++g) {
            float4 v = *(const float4*)&Lb[g*8 + hi*4];
            cc[4*g]=v.x; cc[4*g+1]=v.y; cc[4*g+2]=v.z; cc[4*g+3]=v.w;
        }
    }

    unsigned short* Ob = Oh + ((size_t)bh*2048 + q0 + wid*32)*64;
#pragma unroll
    for (int r = 0; r < 16; ++r) {
        int qr = (r&3) + 8*(r>>2) + 4*hi;
        float inv = 1.0f / cc[r];
        Ob[(size_t)qr*64 + l31]      = bfu(o0[r] * inv);
        Ob[(size_t)qr*64 + 32 + l31] = bfu(o1[r] * inv);
    }
}

// ---------------------------------------------------------------------------
extern "C" void kernel_launch(void* const* d_in, const int* in_sizes, int n_in,
                              void* d_out, int out_size, void* d_ws, size_t ws_size,
                              hipStream_t stream)
{
    const float* q  = (const float*)d_in[0];
    const float* k  = (const float*)d_in[1];
    const float* v  = (const float*)d_in[2];
    const int* mask = (const int*)d_in[3];
    const float* Wq = (const float*)d_in[4];
    const float* Wk = (const float*)d_in[5];
    const float* Wv = (const float*)d_in[6];
    const float* Wo = (const float*)d_in[7];
    float* out = (float*)d_out;

    // ws (ushort elems): Xb 12M | Wb 4M | Qh 4M | Kg 4M | Vg 4M  = 56MB.
    // Oh aliases Xb (Xb is dead after qkv_kernel).
    unsigned short* Xb = (unsigned short*)d_ws;
    unsigned short* Wb = Xb + (size_t)12582912;
    unsigned short* Qh = Wb + (size_t)4194304;
    unsigned short* Kg = Qh + (size_t)4194304;
    unsigned short* Vg = Kg + (size_t)4194304;
    unsigned short* Oh = Xb;

    conv_kernel<<<dim3(2048,4), 256, 0, stream>>>(q, k, v, Wq, Wk, Wv, Wo, Xb, Wb);
    qkv_kernel<<<dim3(32,8,3), 256, 0, stream>>>(Xb, Wb, Qh, Kg, Vg);
    attn_kernel<<<dim3(16,32), 256, 0, stream>>>(Qh, Kg, Vg, mask, Oh);
    oproj_kernel<<<dim3(32,16), 256, 0, stream>>>(Oh, Wb + (size_t)3145728, out);
}